// Round 13
// baseline (271.627 us; speedup 1.0000x reference)
//
#include <hip/hip_runtime.h>
#include <math.h>

#define IMG  1024
#define TC   128             // tile cols
#define TR   64              // tile rows
#define HALO 12
#define SPP  84              // words/row: 2 front pad + 76 data (words 2..77) + 6 rear pad
#define NPRED (90*SPP)       // buffer rows 0..89 = px rows -1..88 (guard top/bottom)
#define NTW  440             // targ: 88 rows x 5 bit-words
#define SEN2 0x40004000u     // (2.0h,2.0h) sentinel = +inf (all real values <= 1)

// pred: fp16 pair-packed 2 px/word, single LDS buffer, in-place erode
// (read-all -> barrier -> write-all). targ: binary bit-packed 32 px/word.
typedef _Float16 h2 __attribute__((ext_vector_type(2)));
union UH { unsigned u; h2 h; };
__device__ __forceinline__ h2 u2h(unsigned u){ UH x; x.u=u; return x.h; }
__device__ __forceinline__ unsigned h2u(h2 h){ UH x; x.h=h; return x.u; }
__device__ __forceinline__ h2 pmin(h2 a, h2 b){ return __builtin_elementwise_min(a,b); }
__device__ __forceinline__ h2 pmax(h2 a, h2 b){ return __builtin_elementwise_max(a,b); }
__device__ __forceinline__ h2 funnel(h2 hi_src, h2 lo_src){
  return u2h((h2u(lo_src)>>16) | (h2u(hi_src)<<16));
}
__device__ __forceinline__ float sigmoidf(float x){ return 1.0f/(1.0f+__expf(-x)); }
__device__ __forceinline__ h2 unsent(h2 x, h2 onev, h2 zerov){
  h2 t = pmax(x-onev, zerov); return x - t - t;   // 2.0 -> 0, identity on [0,1]
}
__device__ __forceinline__ unsigned ext8b(unsigned a, unsigned b, int sh){
  unsigned long long v = ((unsigned long long)b<<32) | (unsigned long long)a;
  return (unsigned)((v >> sh) & 0xFFull);
}
// 5-pt cross erode of one 8-px quad row
__device__ __forceinline__ uint4 erode5(uint4 rm, uint4 rc, uint4 rn, h2 lw, h2 rv){
  h2 a0=u2h(rc.x), a1=u2h(rc.y), a2=u2h(rc.z), a3=u2h(rc.w);
  h2 v0=pmin(u2h(rm.x), u2h(rn.x));
  h2 v1=pmin(u2h(rm.y), u2h(rn.y));
  h2 v2=pmin(u2h(rm.z), u2h(rn.z));
  h2 v3=pmin(u2h(rm.w), u2h(rn.w));
  h2 f0=funnel(a0,lw), f1=funnel(a1,a0), f2=funnel(a2,a1), f3=funnel(a3,a2), f4=funnel(rv,a3);
  uint4 e;
  e.x=h2u(pmin(pmin(f0,f1),pmin(v0,a0)));
  e.y=h2u(pmin(pmin(f1,f2),pmin(v1,a1)));
  e.z=h2u(pmin(pmin(f2,f3),pmin(v2,a2)));
  e.w=h2u(pmin(pmin(f3,f4),pmin(v3,a3)));
  return e;
}

template<bool BND>
__device__ void pipeline(const float* __restrict__ pred, const int* __restrict__ targ,
                         long base, int gr0, int gc0, int tid,
                         unsigned* P, unsigned* Ta,
                         h2 val[16], h2 skel[16], unsigned &tbits, unsigned &skbits) {
  // ---- stamp guard rows (px -1, 88) and pad cols {0,1,78..83} ----
  for (int i = tid; i < 168; i += 256) {
    int r = (i < 84) ? 0 : 89, c = (i < 84) ? i : i - 84;
    P[r*SPP + c] = SEN2;
  }
  for (int i = tid; i < 704; i += 256) {
    int r = 1 + (i >> 3), w = i & 7;
    w = (w < 2) ? w : 76 + w;
    P[r*SPP + w] = SEN2;
  }
  // ---- global -> LDS ----
  if (!BND) {
    #pragma unroll
    for (int k=0;k<7;++k){
      int u = tid + (k<<8);
      if (u < 1672){                         // 88 rows x 19 groups of 8 px
        int r = u/19, q = u - r*19;
        long g = base + (long)(gr0+r)*IMG + gc0 + (q<<3);
        float4 pa = *(const float4*)(pred+g);
        float4 pb = *(const float4*)(pred+g+4);
        h2 w0 = {(_Float16)sigmoidf(pa.x), (_Float16)sigmoidf(pa.y)};
        h2 w1 = {(_Float16)sigmoidf(pa.z), (_Float16)sigmoidf(pa.w)};
        h2 w2 = {(_Float16)sigmoidf(pb.x), (_Float16)sigmoidf(pb.y)};
        h2 w3 = {(_Float16)sigmoidf(pb.z), (_Float16)sigmoidf(pb.w)};
        int o = (1+r)*SPP + 2 + (q<<2);
        uint2 d0; d0.x=h2u(w0); d0.y=h2u(w1);
        uint2 d1; d1.x=h2u(w2); d1.y=h2u(w3);
        *(uint2*)&P[o]   = d0;
        *(uint2*)&P[o+2] = d1;
      }
    }
    #pragma unroll
    for (int k=0;k<2;++k){
      int u = tid + (k<<8);
      if (u < NTW){                          // 88 rows x 5 bit-words
        int r = u/5, w = u - r*5;
        long g = base + (long)(gr0+r)*IMG + gc0 + (w<<5);
        unsigned bits = 0;
        #pragma unroll
        for (int i=0;i<8;++i){
          if (w < 4 || i < 6) {
            int4 tv = *(const int4*)(targ + g + (i<<2));
            unsigned nib = (unsigned)(tv.x!=0) | ((unsigned)(tv.y!=0)<<1)
                         | ((unsigned)(tv.z!=0)<<2) | ((unsigned)(tv.w!=0)<<3);
            bits |= nib << (i<<2);
          }
        }
        if (w==4) bits |= 0xFF000000u;       // pseudo px 152..159: erode-neutral 1
        Ta[u] = bits;
      }
    }
  } else {
    for (int i=tid; i<88*76; i+=256){
      int r = i/76, wd = i - r*76;
      int gr = gr0 + r;
      bool rok = (unsigned)gr < (unsigned)IMG;
      int gca = gc0 + (wd<<1), gcb = gca + 1;
      _Float16 va = (_Float16)2.0f, vb = (_Float16)2.0f;
      if (rok && (unsigned)gca < (unsigned)IMG) va = (_Float16)sigmoidf(pred[base + (long)gr*IMG + gca]);
      if (rok && (unsigned)gcb < (unsigned)IMG) vb = (_Float16)sigmoidf(pred[base + (long)gr*IMG + gcb]);
      h2 w; w.x = va; w.y = vb;
      P[(1+r)*SPP + 2 + wd] = h2u(w);
    }
    for (int u=tid; u<NTW; u+=256){
      int r = u/5, w = u - r*5;
      int gr = gr0 + r;
      bool rok = (unsigned)gr < (unsigned)IMG;
      unsigned bits = 0;
      for (int b=0;b<32;++b){
        int c = (w<<5) + b;
        unsigned bit = 1;
        if (c < 152) {
          int gc = gc0 + c;
          if (rok && (unsigned)gc < (unsigned)IMG) bit = (unsigned)(targ[base+(long)gr*IMG+gc] != 0);
        }
        bits |= bit << b;
      }
      Ta[u] = bits;
    }
  }
  __syncthreads();

  // col validity masks (BND)
  unsigned cm[5] = {~0u,~0u,~0u,~0u,0x00FFFFFFu};
  bool colO = false;
  if (BND) {
    int lo = (-gc0 > 0) ? -gc0 : 0;
    int hi = (IMG - gc0 < 152) ? (IMG - gc0) : 152;
    colO = (lo > 0) || (hi < 152);
    #pragma unroll
    for (int w=0; w<5; ++w){
      int l = lo - (w<<5); if (l<0) l=0;
      int h = hi - (w<<5); if (h>32) h=32;
      unsigned mm = 0;
      if (h > l) {
        unsigned top = (h>=32)? ~0u : ((1u<<h)-1u);
        unsigned bot = (l<=0)? 0u : ((1u<<l)-1u);
        mm = top & ~bot;
      }
      cm[w] = mm;
    }
    cm[4] &= 0x00FFFFFFu;
  }

  // erode ownership: 11 tall-8 strips x 20 quads = 220 units (single unit/thread)
  const bool eact = (tid < 220);
  const int es = tid / 20, eq = tid - es*20;
  const int s8 = es << 3;               // first erode px row of strip (0..80)
  const int ew = eq << 2;               // quad words 0..79 (incl. pads)
  const int cqh = (eq<<3) + 3;          // quad's highest px col
  const int cql = (eq<<3) - 4;          // quad's lowest px col
  // targ erode: words 5..434 (rows 1..86): o1 = 5+tid, o2 = 261+tid
  const int o1 = 5 + tid;
  const int twd1 = tid - (tid/5)*5;
  const bool t2 = (tid < 174);
  const int o2 = 261 + tid;
  const int twd2 = (tid+1) - ((tid+1)/5)*5;

  // dilate/interior ownership: 4 rows x 8 px per thread
  const int qd = tid & 15;              // quad col 0..15
  const int rg = tid >> 4;              // 0..15
  const int r0 = HALO + (rg<<2);        // px rows 12..72 (own r0..r0+3)
  const int wq = 8 + (qd<<2);           // words 8..68 (px 12..139)
  const int bp = HALO + (qd<<3);        // bit position 12..132
  const int bw0 = bp >> 5, bsh = bp & 31;

  h2 ep[16];
  #pragma unroll
  for (int r=0;r<4;++r){
    uint4 c = *(const uint4*)&P[(r0+1+r)*SPP + wq];
    ep[4*r+0]=u2h(c.x); ep[4*r+1]=u2h(c.y); ep[4*r+2]=u2h(c.z); ep[4*r+3]=u2h(c.w);
  }
  #pragma unroll
  for (int i=0;i<16;++i){ val[i]=ep[i]; skel[i]=(h2)(_Float16)0.0f; }
  tbits = 0;
  #pragma unroll
  for (int r=0;r<4;++r){
    int row = r0 + r;
    unsigned b2 = (bw0 < 4) ? Ta[5*row + bw0 + 1] : 0u;
    tbits |= ext8b(Ta[5*row + bw0], b2, bsh) << (r<<3);
  }
  // targ dilate state (threads 0..63, one interior row each)
  unsigned tp[5]={0,0,0,0,0}, sk[5]={0,0,0,0,0};
  const bool td = (tid < 64);
  const int tro = 5*(12 + tid);
  if (td){ 
    #pragma unroll
    for (int w=0;w<5;++w) tp[w]=Ta[tro+w];
  }

  const h2 onev  = {(_Float16)1.0f,(_Float16)1.0f};
  const h2 zerov = {(_Float16)0.0f,(_Float16)0.0f};

  for (int j=0;j<11;++j){
    // ---- erode reads + compute (rolling 3-row window, results in regs) ----
    uint4 e[8];
    const bool act = eact && (s8+7 >= j+1) && (s8 <= 86-j)
                          && (cqh >= j+1) && (cql <= 150-j);
    if (act){
      uint4 rm = *(const uint4*)&P[s8*SPP + ew];        // px row s8-1
      uint4 rc = *(const uint4*)&P[(s8+1)*SPP + ew];    // px row s8
      #pragma unroll
      for (int t=0;t<8;++t){
        uint4 rn = *(const uint4*)&P[(s8+2+t)*SPP + ew];
        h2 lw = u2h(P[(s8+1+t)*SPP + ew - 1]);
        h2 rv = u2h(P[(s8+1+t)*SPP + ew + 4]);
        e[t] = erode5(rm, rc, rn, lw, rv);
        rm = rc; rc = rn;
      }
    }
    // ---- targ erode (read+compute) ----
    unsigned tr1, tr2;
    {
      unsigned own=Ta[o1], up=Ta[o1-5], dn=Ta[o1+5];
      unsigned le = (twd1>0)? Ta[o1-1] : ~0u;
      unsigned ri = (twd1<4)? Ta[o1+1] : ~0u;
      unsigned h = own & ((own>>1)|(ri<<31)) & ((own<<1)|(le>>31));
      tr1 = h & up & dn;
    }
    if (t2){
      unsigned own=Ta[o2], up=Ta[o2-5], dn=Ta[o2+5];
      unsigned le = (twd2>0)? Ta[o2-1] : ~0u;
      unsigned ri = (twd2<4)? Ta[o2+1] : ~0u;
      unsigned h = own & ((own>>1)|(ri<<31)) & ((own<<1)|(le>>31));
      tr2 = h & up & dn;
    }
    __syncthreads();
    // ---- writes ----
    if (act){
      #pragma unroll
      for (int t=0;t<8;++t)
        *(uint4*)&P[(s8+1+t)*SPP + ew] = e[t];
    }
    Ta[o1] = tr1;
    if (t2) Ta[o2] = tr2;
    __syncthreads();

    if (BND) {  // re-stamp OOB to erode-neutral sentinel
      if (gr0 < 0) {
        for (int i=tid;i<912;i+=256){ int r=i/76; P[(1+r)*SPP+2+(i-r*76)] = SEN2; }
        if (tid < 60) Ta[tid] = ~0u;
      }
      if (gr0 + 88 > IMG) {
        for (int i=tid;i<912;i+=256){ int r=i/76; P[(77+r)*SPP+2+(i-r*76)] = SEN2; }
        if (tid < 60) Ta[380+tid] = ~0u;
      }
      if (colO) {
        if (gc0 < 0)
          for (int i=tid;i<528;i+=256){ int r=i/6; P[(1+r)*SPP+2+(i-r*6)] = SEN2; }
        if (gc0 + 152 > IMG)
          for (int i=tid;i<528;i+=256){ int r=i/6; P[(1+r)*SPP+72+(i-r*6)] = SEN2; }
        for (int i=tid;i<NTW;i+=256){
          int r=i/5, w=i-r*5;
          Ta[i] |= ~cm[w];
        }
      }
      __syncthreads();
    }

    // ---- pred 3x3 dilate at own 4x8 px + skel update (reads P = e_{j+1}) ----
    h2 H[6][4];
    uint4 cap[4];
    #pragma unroll
    for (int k=0;k<6;++k){
      int ro = (r0+k)*SPP + wq;             // px rows r0-1 .. r0+4
      uint4 c = *(const uint4*)&P[ro];
      h2 lwv = u2h(P[ro-1]);
      h2 rwv = u2h(P[ro+4]);
      if (k>=1 && k<=4) cap[k-1] = c;
      h2 a0=u2h(c.x),a1=u2h(c.y),a2=u2h(c.z),a3=u2h(c.w);
      if (BND){
        a0=unsent(a0,onev,zerov); a1=unsent(a1,onev,zerov);
        a2=unsent(a2,onev,zerov); a3=unsent(a3,onev,zerov);
        lwv=unsent(lwv,onev,zerov); rwv=unsent(rwv,onev,zerov);
      }
      h2 f0=funnel(a0,lwv), f1=funnel(a1,a0), f2=funnel(a2,a1), f3=funnel(a3,a2), f4=funnel(rwv,a3);
      H[k][0]=pmax(pmax(f0,f1),a0);
      H[k][1]=pmax(pmax(f1,f2),a1);
      H[k][2]=pmax(pmax(f2,f3),a2);
      H[k][3]=pmax(pmax(f3,f4),a3);
    }
    #pragma unroll
    for (int r=0;r<4;++r){
      #pragma unroll
      for (int i=0;i<4;++i){
        h2 m = pmax(pmax(H[r][i],H[r+1][i]),H[r+2][i]);
        h2 d = pmax(ep[4*r+i]-m, zerov);
        h2 x = d - skel[4*r+i]*d;
        skel[4*r+i] = skel[4*r+i] + pmax(x, zerov);
      }
    }
    #pragma unroll
    for (int r=0;r<4;++r){
      ep[4*r+0]=u2h(cap[r].x); ep[4*r+1]=u2h(cap[r].y);
      ep[4*r+2]=u2h(cap[r].z); ep[4*r+3]=u2h(cap[r].w);
    }

    // ---- targ dilate + skel_t ----
    if (td) {
      unsigned o[5], u[5], n[5], v[5];
      #pragma unroll
      for (int w=0;w<5;++w){ o[w]=Ta[tro+w]; u[w]=Ta[tro-5+w]; n[w]=Ta[tro+5+w]; }
      if (BND){
        unsigned mu = ((unsigned)(gr0 + 11 + tid) < (unsigned)IMG) ? ~0u : 0u;
        unsigned md = ((unsigned)(gr0 + 13 + tid) < (unsigned)IMG) ? ~0u : 0u;
        #pragma unroll
        for (int w=0;w<5;++w) v[w] = ((u[w]&mu)|o[w]|(n[w]&md)) & cm[w];
      } else {
        #pragma unroll
        for (int w=0;w<5;++w) v[w] = u[w]|o[w]|n[w];
      }
      unsigned d0 = v[0] | (v[0]<<1) | (v[0]>>1) | (v[1]<<31);
      unsigned d1 = v[1] | (v[1]<<1) | (v[0]>>31) | (v[1]>>1) | (v[2]<<31);
      unsigned d2 = v[2] | (v[2]<<1) | (v[1]>>31) | (v[2]>>1) | (v[3]<<31);
      unsigned d3 = v[3] | (v[3]<<1) | (v[2]>>31) | (v[3]>>1) | (v[4]<<31);
      unsigned d4 = v[4] | (v[4]<<1) | (v[3]>>31) | (v[4]>>1);
      sk[0] |= tp[0] & ~d0;  sk[1] |= tp[1] & ~d1;  sk[2] |= tp[2] & ~d2;
      sk[3] |= tp[3] & ~d3;  sk[4] |= tp[4] & ~d4;
      #pragma unroll
      for (int w=0;w<5;++w) tp[w] = o[w];
    }
  }

  __syncthreads();
  if (td){
    #pragma unroll
    for (int w=0;w<5;++w) Ta[5*tid+w] = sk[w];
  }
  __syncthreads();
  skbits = 0;
  #pragma unroll
  for (int r=0;r<4;++r){
    int row = (rg<<2) + r;
    unsigned b2 = (bw0 < 4) ? Ta[5*row + bw0 + 1] : 0u;
    skbits |= ext8b(Ta[5*row + bw0], b2, bsh) << (r<<3);
  }
}

__global__ __launch_bounds__(256,4)
void cl_dice_main(const float* __restrict__ pred, const int* __restrict__ targ,
                  float* __restrict__ ws) {
  __shared__ alignas(16) unsigned sP[NPRED];
  __shared__ unsigned sTA[NTW];
  const int tid = threadIdx.x;
  const int gr0 = blockIdx.y * TR - HALO;
  const int gc0 = blockIdx.x * TC - HALO;
  const long base = (long)blockIdx.z * (long)(IMG * IMG);

  h2 val[16], skel[16]; unsigned tbits, skbits;
  const bool bnd = (blockIdx.x == 0) | (blockIdx.x == gridDim.x - 1) |
                   (blockIdx.y == 0) | (blockIdx.y == gridDim.y - 1);
  if (!bnd) pipeline<false>(pred, targ, base, gr0, gc0, tid, sP, sTA, val, skel, tbits, skbits);
  else      pipeline<true >(pred, targ, base, gr0, gc0, tid, sP, sTA, val, skel, tbits, skbits);

  float s[7] = {0,0,0,0,0,0,0};
  #pragma unroll
  for (int k=0;k<16;++k){
    int bb = ((k>>2)<<3) + ((k&3)<<1);
    float p0=(float)val[k].x,  p1=(float)val[k].y;
    float a0=(float)skel[k].x, a1=(float)skel[k].y;
    float t0=(float)((tbits>>bb)&1u),  t1=(float)((tbits>>(bb+1))&1u);
    float b0=(float)((skbits>>bb)&1u), b1=(float)((skbits>>(bb+1))&1u);
    s[0]+=a0+a1;        s[1]+=a0*t0+a1*t1;
    s[2]+=b0+b1;        s[3]+=b0*p0+b1*p1;
    s[4]+=p0*t0+p1*t1;  s[5]+=p0+p1;  s[6]+=t0+t1;
  }

  float* red = (float*)sP;
  #pragma unroll
  for (int k=0;k<7;++k){
    float v = s[k];
    v += __shfl_down(v,32); v += __shfl_down(v,16); v += __shfl_down(v,8);
    v += __shfl_down(v,4);  v += __shfl_down(v,2);  v += __shfl_down(v,1);
    if ((tid & 63) == 0) red[(tid>>6)*8 + k] = v;
  }
  __syncthreads();
  if (tid < 7) {
    float v = red[tid] + red[8+tid] + red[16+tid] + red[24+tid];
    int blk = (blockIdx.z * gridDim.y + blockIdx.y) * gridDim.x + blockIdx.x;
    ws[blk*8 + tid] = v;
  }
}

__global__ __launch_bounds__(256)
void cl_dice_finalize(const float* __restrict__ ws, float* __restrict__ out, int nblk) {
  __shared__ float red[4][8];
  int tid = threadIdx.x;
  float acc[7] = {0,0,0,0,0,0,0};
  for (int i=tid; i<nblk; i+=256) {
    #pragma unroll
    for (int k=0;k<7;++k) acc[k] += ws[i*8 + k];
  }
  #pragma unroll
  for (int k=0;k<7;++k){
    float v = acc[k];
    v += __shfl_down(v,32); v += __shfl_down(v,16); v += __shfl_down(v,8);
    v += __shfl_down(v,4);  v += __shfl_down(v,2);  v += __shfl_down(v,1);
    if ((tid & 63) == 0) red[tid>>6][k] = v;
  }
  __syncthreads();
  if (tid == 0) {
    float t0[7];
    #pragma unroll
    for (int k=0;k<7;++k) t0[k] = red[0][k] + red[1][k] + red[2][k] + red[3][k];
    float sum_sp = t0[0], sum_spt = t0[1], sum_st = t0[2], sum_stp = t0[3];
    float inter  = t0[4], sum_p   = t0[5], sum_t  = t0[6];
    float tprec = (sum_spt + 1.0f) / (sum_sp + 1.0f);
    float tsens = (sum_stp + 1.0f) / (sum_st + 1.0f);
    float cl    = 2.0f * tprec * tsens / (tprec + tsens + 1e-7f);
    float dice  = (2.0f * inter + 1.0f) / (sum_p + sum_t + 1.0f);
    out[0] = 1.0f - 0.5f * (dice + cl);
  }
}

extern "C" void kernel_launch(void* const* d_in, const int* in_sizes, int n_in,
                              void* d_out, int out_size, void* d_ws, size_t ws_size,
                              hipStream_t stream) {
  const float* pred = (const float*)d_in[0];
  const int*   targ = (const int*)d_in[1];
  float* ws  = (float*)d_ws;
  float* out = (float*)d_out;

  const int B = in_sizes[0] / (IMG * IMG);     // 8
  dim3 grid(IMG / TC, IMG / TR, B);            // 8 x 16 x 8 = 1024 blocks
  cl_dice_main<<<grid, 256, 0, stream>>>(pred, targ, ws);

  const int nblk = (IMG / TC) * (IMG / TR) * B;
  cl_dice_finalize<<<1, 256, 0, stream>>>(ws, out, nblk);
}